// Round 1
// baseline (230.738 us; speedup 1.0000x reference)
//
#include <hip/hip_runtime.h>
#include <stdint.h>

typedef unsigned short ushort_t;
typedef __attribute__((ext_vector_type(8))) __bf16 bf16x8;
typedef __attribute__((ext_vector_type(4))) float  f32x4;

// ---------- helpers ----------

__device__ __forceinline__ unsigned int f2bf(float f) {
    unsigned int u = __float_as_uint(f);
    return (u + 0x7FFFu + ((u >> 16) & 1u)) >> 16;  // RNE
}

// Cayley sign for e_a * e_b in Cl(4,1), SIG = [1,1,1,1,-1]
__device__ __forceinline__ float cayley_sign(int a, int b) {
    int s = 0;
    int aa = a >> 1;
    while (aa) { s += __popc(aa & b); aa >>= 1; }
    float sign = (s & 1) ? -1.0f : 1.0f;
    if (a & b & 16) sign = -sign;   // only SIG[4] = -1
    return sign;
}

// async global->LDS, 16 bytes per lane. LDS dest is wave-uniform base + lane*16.
__device__ __forceinline__ void async16(const ushort_t* g, const ushort_t* l) {
    const __attribute__((address_space(1))) unsigned int* gp =
        (const __attribute__((address_space(1))) unsigned int*)(uintptr_t)g;
    __attribute__((address_space(3))) unsigned int* lp =
        (__attribute__((address_space(3))) unsigned int*)(unsigned int)(uintptr_t)l;
    __builtin_amdgcn_global_load_lds(gp, lp, 16, 0, 0);
}

// ---------- merged prep kernel (coalesced) ----------
// Operand image = exact LDS image the GEMM wants, per (panel P of 256 rows,
// k-tile kt of 64): 16384 bf16 laid out [k8(8)][row(256)][j(8)], k = k8*8+j.
// Each 16 KiB half (k8 0..3 / 4..7) is one global_load_lds "half-tile".
__global__ __launch_bounds__(256) void prepAB(const float* __restrict__ x,
                                              const float* __restrict__ w,
                                              ushort_t* __restrict__ A_sw,
                                              ushort_t* __restrict__ B_sw) {
    const int k_blk = blockIdx.x;            // 0..127 (32-k chunk)
    const int p_blk = blockIdx.y >> 1;       // 0..31 (128-row panel)
    const int sub   = blockIdx.y & 1;        // 0..1  (64-row half)
    const int t = threadIdx.x;               // 0..255
    const int r  = sub * 64 + (t >> 2);      // 0..127 row/col within 128-panel
    const int kq = t & 3;                    // 0..3

    const int kt = k_blk >> 1;               // 64-k tile index (0..63)
    const int kh = k_blk & 1;                // which 32-k half of the tile

    if (blockIdx.z == 0) {
        // ---- A: x viewed as 4096 x 4096 row-major f32 -> bf16 swizzled ----
        const int R = p_blk * 128 + r;
        const float* src = x + (size_t)R * 4096 + (size_t)k_blk * 32 + kq * 8;
        float4 a = ((const float4*)src)[0];
        float4 b = ((const float4*)src)[1];
        uint4 pk;
        pk.x = f2bf(a.x) | (f2bf(a.y) << 16);
        pk.y = f2bf(a.z) | (f2bf(a.w) << 16);
        pk.z = f2bf(b.x) | (f2bf(b.y) << 16);
        pk.w = f2bf(b.z) | (f2bf(b.w) << 16);
        const int P = R >> 8, rowp = R & 255;
        *(uint4*)(A_sw + (size_t)(P * 64 + kt) * 16384 + kh * 8192 + kq * 2048 + rowp * 8) = pk;
    } else {
        // ---- B: Bt[n][f*32+i] = W[o, f, i^kc] * sgn(i, i^kc), n = o*32+kc ----
        const int n = p_blk * 128 + r;
        const int o = n >> 5;
        const int kc = n & 31;
        const float* wrow = w + (size_t)o * 4096 + (size_t)k_blk * 32;
        unsigned int pk[4];
#pragma unroll
        for (int pr = 0; pr < 4; ++pr) {
            const int i0 = kq * 8 + pr * 2, i1 = i0 + 1;
            const int j0 = i0 ^ kc, j1 = i1 ^ kc;
            float v0 = wrow[j0] * cayley_sign(i0, j0);
            float v1 = wrow[j1] * cayley_sign(i1, j1);
            pk[pr] = f2bf(v0) | (f2bf(v1) << 16);
        }
        uint4 u = {pk[0], pk[1], pk[2], pk[3]};
        const int P = n >> 8, colp = n & 255;
        *(uint4*)(B_sw + (size_t)(P * 64 + kt) * 16384 + kh * 8192 + kq * 2048 + colp * 8) = u;
    }
}

// ---------- GEMM: 256x256 tile, BK=64, 8 waves, 8-phase counted-vmcnt ----------
// 16x16x32 bf16 MFMA. Per wave: 128 rows x 64 cols -> acc[8][4] f32x4.
// Phase (TMB, KH): 4 A-frag ds_reads (+4 B-frag reads when KH flips),
// 1 half-tile global_load_lds prefetch, barrier, lgkmcnt(0), 16 MFMA, barrier.
// vmcnt(4) once per K-tile (never 0 in steady state).

#define MFMA16(a, b, c) __builtin_amdgcn_mfma_f32_16x16x32_bf16(a, b, c, 0, 0, 0)

#define BLOAD(OFS) do {                                                        \
        bF[0] = *(const bf16x8*)(Bc + bOff + (OFS) + 0 * 128);                 \
        bF[1] = *(const bf16x8*)(Bc + bOff + (OFS) + 1 * 128);                 \
        bF[2] = *(const bf16x8*)(Bc + bOff + (OFS) + 2 * 128);                 \
        bF[3] = *(const bf16x8*)(Bc + bOff + (OFS) + 3 * 128);                 \
    } while (0)

#define GA_PHASE(TMB, KH, PRE_STMT, STAGE_STMT, TAIL_STMT)                     \
    {                                                                          \
        PRE_STMT;                                                              \
        const ushort_t* ap_ = Ac + aOff + (KH) * 8192 + (TMB) * 128;           \
        bf16x8 aF0 = *(const bf16x8*)(ap_ + 0 * 128);                          \
        bf16x8 aF1 = *(const bf16x8*)(ap_ + 1 * 128);                          \
        bf16x8 aF2 = *(const bf16x8*)(ap_ + 2 * 128);                          \
        bf16x8 aF3 = *(const bf16x8*)(ap_ + 3 * 128);                          \
        STAGE_STMT;                                                            \
        __builtin_amdgcn_s_barrier();                                          \
        asm volatile("s_waitcnt lgkmcnt(0)" ::: "memory");                     \
        __builtin_amdgcn_s_setprio(1);                                         \
        acc[(TMB) + 0][0] = MFMA16(aF0, bF[0], acc[(TMB) + 0][0]);             \
        acc[(TMB) + 0][1] = MFMA16(aF0, bF[1], acc[(TMB) + 0][1]);             \
        acc[(TMB) + 0][2] = MFMA16(aF0, bF[2], acc[(TMB) + 0][2]);             \
        acc[(TMB) + 0][3] = MFMA16(aF0, bF[3], acc[(TMB) + 0][3]);             \
        acc[(TMB) + 1][0] = MFMA16(aF1, bF[0], acc[(TMB) + 1][0]);             \
        acc[(TMB) + 1][1] = MFMA16(aF1, bF[1], acc[(TMB) + 1][1]);             \
        acc[(TMB) + 1][2] = MFMA16(aF1, bF[2], acc[(TMB) + 1][2]);             \
        acc[(TMB) + 1][3] = MFMA16(aF1, bF[3], acc[(TMB) + 1][3]);             \
        acc[(TMB) + 2][0] = MFMA16(aF2, bF[0], acc[(TMB) + 2][0]);             \
        acc[(TMB) + 2][1] = MFMA16(aF2, bF[1], acc[(TMB) + 2][1]);             \
        acc[(TMB) + 2][2] = MFMA16(aF2, bF[2], acc[(TMB) + 2][2]);             \
        acc[(TMB) + 2][3] = MFMA16(aF2, bF[3], acc[(TMB) + 2][3]);             \
        acc[(TMB) + 3][0] = MFMA16(aF3, bF[0], acc[(TMB) + 3][0]);             \
        acc[(TMB) + 3][1] = MFMA16(aF3, bF[1], acc[(TMB) + 3][1]);             \
        acc[(TMB) + 3][2] = MFMA16(aF3, bF[2], acc[(TMB) + 3][2]);             \
        acc[(TMB) + 3][3] = MFMA16(aF3, bF[3], acc[(TMB) + 3][3]);             \
        __builtin_amdgcn_s_setprio(0);                                         \
        TAIL_STMT;                                                             \
        __builtin_amdgcn_s_barrier();                                          \
    }

__global__ __launch_bounds__(512, 2) void gemm_norm(const ushort_t* __restrict__ A_sw,
                                                    const ushort_t* __restrict__ B_sw,
                                                    float* __restrict__ out) {
    __shared__ ushort_t As[2][16384];   // 2 x 32 KiB
    __shared__ ushort_t Bs[2][16384];   // 2 x 32 KiB  (128 KiB total, 1 block/CU)

    // XCD-aware bijective swizzle over the 256-block grid (256 % 8 == 0)
    int id = blockIdx.x;
    id = (id & 7) * 32 + (id >> 3);
    const int m_blk = id >> 4;          // 0..15
    const int n_blk = id & 15;          // 0..15

    const int t    = threadIdx.x;
    const int wave = t >> 6;            // 0..7
    const int lane = t & 63;
    const int wr = wave >> 2;           // 0..1  (row half of 256)
    const int wc = wave & 3;            // 0..3  (64-col slice)
    const int lg = lane >> 4;           // 0..3  (k-quarter within 32-chunk)
    const int lm = lane & 15;           // 0..15 (m/n within 16-tile)

    const int aOff = (lg * 256 + wr * 128 + lm) * 8;   // elem offset into A image
    const int bOff = (lg * 256 + wc * 64  + lm) * 8;   // elem offset into B image

    const ushort_t* aPanel = A_sw + (size_t)m_blk * 64 * 16384;
    const ushort_t* bPanel = B_sw + (size_t)n_blk * 64 * 16384;

    f32x4 acc[8][4];
#pragma unroll
    for (int i = 0; i < 8; ++i)
#pragma unroll
        for (int j = 0; j < 4; ++j)
#pragma unroll
            for (int k = 0; k < 4; ++k) acc[i][j][k] = 0.0f;

    const int so = wave * 1024 + lane * 8;  // per-lane global elem offset of stage slice
    const int sl = wave * 1024;             // wave-uniform LDS elem offset

    auto STAGE2 = [&](const ushort_t* src, const ushort_t* ldsb) {
        async16(src + so,       ldsb + sl);
        async16(src + so + 512, ldsb + sl + 512);
    };

    const int NT = 64;

    // prologue: B(0), A(0), B(1) = 6 half-tiles, 12 loads; wait oldest 8 (tile 0).
    STAGE2(bPanel + 0,            &Bs[0][0]);
    STAGE2(bPanel + 8192,         &Bs[0][8192]);
    STAGE2(aPanel + 0,            &As[0][0]);
    STAGE2(aPanel + 8192,         &As[0][8192]);
    STAGE2(bPanel + 16384,        &Bs[1][0]);
    STAGE2(bPanel + 16384 + 8192, &Bs[1][8192]);
    asm volatile("s_waitcnt vmcnt(4)" ::: "memory");
    __builtin_amdgcn_s_barrier();

#pragma unroll 2
    for (int tt = 0; tt < NT; ++tt) {
        const int b = tt & 1;
        const ushort_t* Ac = &As[b][0];
        const ushort_t* Bc = &Bs[b][0];
        ushort_t* An = &As[b ^ 1][0];   // A(t+1) target
        ushort_t* Bn = &Bs[b][0];       // B(t+2) target (same parity as t)

        bf16x8 bF[4];

        // phase 0: tm 0-3, kh 0; load B kh0; stage A-half0(t+1)
        GA_PHASE(0, 0, BLOAD(0),
                 if (tt + 1 < NT) STAGE2(aPanel + (size_t)(tt + 1) * 16384, An),
                 {})
        // phase 1: tm 4-7, kh 0; stage A-half1(t+1)
        GA_PHASE(4, 0, {},
                 if (tt + 1 < NT) STAGE2(aPanel + (size_t)(tt + 1) * 16384 + 8192, An + 8192),
                 {})
        // phase 2: tm 0-3, kh 1; load B kh1; stage B-half0(t+2)
        GA_PHASE(0, 1, BLOAD(8192),
                 if (tt + 2 < NT) STAGE2(bPanel + (size_t)(tt + 2) * 16384, Bn),
                 {})
        // phase 3: tm 4-7, kh 1; stage B-half1(t+2); counted per-tile wait
        GA_PHASE(4, 1, {},
                 if (tt + 2 < NT) STAGE2(bPanel + (size_t)(tt + 2) * 16384 + 8192, Bn + 8192),
                 { if (tt < NT - 2)       asm volatile("s_waitcnt vmcnt(4)" ::: "memory");
                   else if (tt == NT - 2) asm volatile("s_waitcnt vmcnt(0)" ::: "memory"); })
    }

    // ---------- fused multivector normalization + store ----------
    // C/D 16x16 layout: col = lane&15, row = (lane>>4)*4 + reg.
    // A multivector = 32 consecutive cols = col-tile pair (2u, 2u+1).
    const int row0 = m_blk * 256 + wr * 128;
    const int col0 = n_blk * 256 + wc * 64;
#pragma unroll
    for (int tm = 0; tm < 8; ++tm) {
#pragma unroll
        for (int u = 0; u < 2; ++u) {
#pragma unroll
            for (int reg = 0; reg < 4; ++reg) {
                float v0 = acc[tm][2 * u][reg];
                float v1 = acc[tm][2 * u + 1][reg];
                float p = v0 * v0 + v1 * v1;
                p += __shfl_xor(p, 1);
                p += __shfl_xor(p, 2);
                p += __shfl_xor(p, 4);
                p += __shfl_xor(p, 8);      // stays within the 16-lane group
                const float inv = rsqrtf(p + 1e-6f);
                const int row = row0 + tm * 16 + lg * 4 + reg;
                float* orow = out + (size_t)row * 4096 + col0 + u * 32 + lm;
                orow[0]  = v0 * inv;
                orow[16] = v1 * inv;
            }
        }
    }
}

// ---------- launch ----------

extern "C" void kernel_launch(void* const* d_in, const int* in_sizes, int n_in,
                              void* d_out, int out_size, void* d_ws, size_t ws_size,
                              hipStream_t stream) {
    const float* x = (const float*)d_in[0];     // 4096 x 128 x 32 f32
    const float* w = (const float*)d_in[1];     // 128 x 128 x 32 f32
    float* out = (float*)d_out;                 // 4096 x 128 x 32 f32

    ushort_t* A_sw = (ushort_t*)d_ws;                       // 32 MiB
    ushort_t* B_sw = A_sw + (size_t)4096 * 4096;            // 32 MiB

    prepAB<<<dim3(128, 64, 2), 256, 0, stream>>>(x, w, A_sw, B_sw);
    gemm_norm<<<dim3(256), 512, 0, stream>>>(A_sw, B_sw, out);
}

// Round 2
// 230.448 us; speedup vs baseline: 1.0013x; 1.0013x over previous
//
#include <hip/hip_runtime.h>
#include <stdint.h>

typedef unsigned short ushort_t;
typedef __attribute__((ext_vector_type(8))) __bf16 bf16x8;
typedef __attribute__((ext_vector_type(4))) float  f32x4;

// ---------- helpers ----------

__device__ __forceinline__ unsigned int f2bf(float f) {
    unsigned int u = __float_as_uint(f);
    return (u + 0x7FFFu + ((u >> 16) & 1u)) >> 16;  // RNE
}

// Cayley sign for e_a * e_b in Cl(4,1), SIG = [1,1,1,1,-1]
__device__ __forceinline__ float cayley_sign(int a, int b) {
    int s = 0;
    int aa = a >> 1;
    while (aa) { s += __popc(aa & b); aa >>= 1; }
    float sign = (s & 1) ? -1.0f : 1.0f;
    if (a & b & 16) sign = -sign;   // only SIG[4] = -1
    return sign;
}

// async global->LDS, 16 bytes per lane. LDS dest is wave-uniform base + lane*16.
__device__ __forceinline__ void async16(const ushort_t* g, const ushort_t* l) {
    const __attribute__((address_space(1))) unsigned int* gp =
        (const __attribute__((address_space(1))) unsigned int*)(uintptr_t)g;
    __attribute__((address_space(3))) unsigned int* lp =
        (__attribute__((address_space(3))) unsigned int*)(unsigned int)(uintptr_t)l;
    __builtin_amdgcn_global_load_lds(gp, lp, 16, 0, 0);
}

// ---------- merged prep kernel (coalesced) ----------
// Operand image = exact LDS image the GEMM wants, per (panel P of 256 rows,
// k-tile kt of 64): 16384 bf16 laid out [k8(8)][row(256)][j(8)], k = k8*8+j.
// Each 16 KiB half (k8 0..3 / 4..7) is one global_load_lds "half-tile".
__global__ __launch_bounds__(256) void prepAB(const float* __restrict__ x,
                                              const float* __restrict__ w,
                                              ushort_t* __restrict__ A_sw,
                                              ushort_t* __restrict__ B_sw) {
    const int k_blk = blockIdx.x;            // 0..127 (32-k chunk)
    const int p_blk = blockIdx.y >> 1;       // 0..31 (128-row panel)
    const int sub   = blockIdx.y & 1;        // 0..1  (64-row half)
    const int t = threadIdx.x;               // 0..255
    const int r  = sub * 64 + (t >> 2);      // 0..127 row/col within 128-panel
    const int kq = t & 3;                    // 0..3

    const int kt = k_blk >> 1;               // 64-k tile index (0..63)
    const int kh = k_blk & 1;                // which 32-k half of the tile

    if (blockIdx.z == 0) {
        // ---- A: x viewed as 4096 x 4096 row-major f32 -> bf16 swizzled ----
        const int R = p_blk * 128 + r;
        const float* src = x + (size_t)R * 4096 + (size_t)k_blk * 32 + kq * 8;
        float4 a = ((const float4*)src)[0];
        float4 b = ((const float4*)src)[1];
        uint4 pk;
        pk.x = f2bf(a.x) | (f2bf(a.y) << 16);
        pk.y = f2bf(a.z) | (f2bf(a.w) << 16);
        pk.z = f2bf(b.x) | (f2bf(b.y) << 16);
        pk.w = f2bf(b.z) | (f2bf(b.w) << 16);
        const int P = R >> 8, rowp = R & 255;
        *(uint4*)(A_sw + (size_t)(P * 64 + kt) * 16384 + kh * 8192 + kq * 2048 + rowp * 8) = pk;
    } else {
        // ---- B: Bt[n][f*32+i] = W[o, f, i^kc] * sgn(i, i^kc), n = o*32+kc ----
        const int n = p_blk * 128 + r;
        const int o = n >> 5;
        const int kc = n & 31;
        const float* wrow = w + (size_t)o * 4096 + (size_t)k_blk * 32;
        unsigned int pk[4];
#pragma unroll
        for (int pr = 0; pr < 4; ++pr) {
            const int i0 = kq * 8 + pr * 2, i1 = i0 + 1;
            const int j0 = i0 ^ kc, j1 = i1 ^ kc;
            float v0 = wrow[j0] * cayley_sign(i0, j0);
            float v1 = wrow[j1] * cayley_sign(i1, j1);
            pk[pr] = f2bf(v0) | (f2bf(v1) << 16);
        }
        uint4 u = {pk[0], pk[1], pk[2], pk[3]};
        const int P = n >> 8, colp = n & 255;
        *(uint4*)(B_sw + (size_t)(P * 64 + kt) * 16384 + kh * 8192 + kq * 2048 + colp * 8) = u;
    }
}

// ---------- GEMM: 256x256 tile, BK=64, 8 waves, deep counted-vmcnt pipeline ----------
// 16x16x32 bf16 MFMA. Per wave: 128 rows x 64 cols -> acc[8][4] f32x4.
// Steady state: one half-tile staged per phase, ~1.5 K-tiles ahead of use:
//   ph0: A(t+1)h1 -> As[b^1]   (As[b^1]h1 dead since iter t-1 ph3)
//   ph1: B(t+2)h0 -> Bs[b]     (Bs[b]h0 dead since ph0)
//   ph2: A(t+2)h0 -> As[b]     (As[b]h0 dead since ph1)
//   ph3: B(t+2)h1 -> Bs[b]     (Bs[b]h1 dead since ph2)
// Waits: vmcnt(10) at end of ph1 (guarantees A(t)h1,B(t)h1 for ph2/3) and
// end of ph3 (guarantees A(t+1)h0,B(t+1)h0 for next iter ph0/1).
// Issue-to-wait distance = 5 phases (~780 cy) for every half-tile.

#define MFMA16(a, b, c) __builtin_amdgcn_mfma_f32_16x16x32_bf16(a, b, c, 0, 0, 0)

#define BLOAD(OFS) do {                                                        \
        bF[0] = *(const bf16x8*)(Bc + bOff + (OFS) + 0 * 128);                 \
        bF[1] = *(const bf16x8*)(Bc + bOff + (OFS) + 1 * 128);                 \
        bF[2] = *(const bf16x8*)(Bc + bOff + (OFS) + 2 * 128);                 \
        bF[3] = *(const bf16x8*)(Bc + bOff + (OFS) + 3 * 128);                 \
    } while (0)

#define GA_PHASE(TMB, KH, PRE_STMT, STAGE_STMT, TAIL_STMT)                     \
    {                                                                          \
        PRE_STMT;                                                              \
        const ushort_t* ap_ = Ac + aOff + (KH) * 8192 + (TMB) * 128;           \
        bf16x8 aF0 = *(const bf16x8*)(ap_ + 0 * 128);                          \
        bf16x8 aF1 = *(const bf16x8*)(ap_ + 1 * 128);                          \
        bf16x8 aF2 = *(const bf16x8*)(ap_ + 2 * 128);                          \
        bf16x8 aF3 = *(const bf16x8*)(ap_ + 3 * 128);                          \
        STAGE_STMT;                                                            \
        __builtin_amdgcn_s_barrier();                                          \
        asm volatile("s_waitcnt lgkmcnt(0)" ::: "memory");                     \
        __builtin_amdgcn_s_setprio(1);                                         \
        acc[(TMB) + 0][0] = MFMA16(aF0, bF[0], acc[(TMB) + 0][0]);             \
        acc[(TMB) + 0][1] = MFMA16(aF0, bF[1], acc[(TMB) + 0][1]);             \
        acc[(TMB) + 0][2] = MFMA16(aF0, bF[2], acc[(TMB) + 0][2]);             \
        acc[(TMB) + 0][3] = MFMA16(aF0, bF[3], acc[(TMB) + 0][3]);             \
        acc[(TMB) + 1][0] = MFMA16(aF1, bF[0], acc[(TMB) + 1][0]);             \
        acc[(TMB) + 1][1] = MFMA16(aF1, bF[1], acc[(TMB) + 1][1]);             \
        acc[(TMB) + 1][2] = MFMA16(aF1, bF[2], acc[(TMB) + 1][2]);             \
        acc[(TMB) + 1][3] = MFMA16(aF1, bF[3], acc[(TMB) + 1][3]);             \
        acc[(TMB) + 2][0] = MFMA16(aF2, bF[0], acc[(TMB) + 2][0]);             \
        acc[(TMB) + 2][1] = MFMA16(aF2, bF[1], acc[(TMB) + 2][1]);             \
        acc[(TMB) + 2][2] = MFMA16(aF2, bF[2], acc[(TMB) + 2][2]);             \
        acc[(TMB) + 2][3] = MFMA16(aF2, bF[3], acc[(TMB) + 2][3]);             \
        acc[(TMB) + 3][0] = MFMA16(aF3, bF[0], acc[(TMB) + 3][0]);             \
        acc[(TMB) + 3][1] = MFMA16(aF3, bF[1], acc[(TMB) + 3][1]);             \
        acc[(TMB) + 3][2] = MFMA16(aF3, bF[2], acc[(TMB) + 3][2]);             \
        acc[(TMB) + 3][3] = MFMA16(aF3, bF[3], acc[(TMB) + 3][3]);             \
        __builtin_amdgcn_s_setprio(0);                                         \
        TAIL_STMT;                                                             \
        __builtin_amdgcn_s_barrier();                                          \
    }

__global__ __launch_bounds__(512, 2) void gemm_norm(const ushort_t* __restrict__ A_sw,
                                                    const ushort_t* __restrict__ B_sw,
                                                    float* __restrict__ out) {
    __shared__ ushort_t As[2][16384];   // 2 x 32 KiB
    __shared__ ushort_t Bs[2][16384];   // 2 x 32 KiB  (128 KiB total, 1 block/CU)

    // XCD-aware bijective swizzle over the 256-block grid (256 % 8 == 0)
    int id = blockIdx.x;
    id = (id & 7) * 32 + (id >> 3);
    const int m_blk = id >> 4;          // 0..15
    const int n_blk = id & 15;          // 0..15

    const int t    = threadIdx.x;
    const int wave = t >> 6;            // 0..7
    const int lane = t & 63;
    const int wr = wave >> 2;           // 0..1  (row half of 256)
    const int wc = wave & 3;            // 0..3  (64-col slice)
    const int lg = lane >> 4;           // 0..3  (k-quarter within 32-chunk)
    const int lm = lane & 15;           // 0..15 (m/n within 16-tile)

    const int aOff = (lg * 256 + wr * 128 + lm) * 8;   // elem offset into A image
    const int bOff = (lg * 256 + wc * 64  + lm) * 8;   // elem offset into B image

    const ushort_t* aPanel = A_sw + (size_t)m_blk * 64 * 16384;
    const ushort_t* bPanel = B_sw + (size_t)n_blk * 64 * 16384;

    f32x4 acc[8][4];
#pragma unroll
    for (int i = 0; i < 8; ++i)
#pragma unroll
        for (int j = 0; j < 4; ++j)
#pragma unroll
            for (int k = 0; k < 4; ++k) acc[i][j][k] = 0.0f;

    const int so = wave * 1024 + lane * 8;  // per-lane global elem offset of stage slice
    const int sl = wave * 1024;             // wave-uniform LDS elem offset

    auto STAGE2 = [&](const ushort_t* src, ushort_t* ldsb) {
        async16(src + so,       ldsb + sl);
        async16(src + so + 512, ldsb + sl + 512);
    };

    const int NT = 64;

    // prologue, in steady-state issue order (7 half-tiles, 14 loads):
    // B(0)h0, A(0)h0, B(0)h1, A(0)h1, B(1)h0, A(1)h0, B(1)h1
    STAGE2(bPanel + 0,             &Bs[0][0]);
    STAGE2(aPanel + 0,             &As[0][0]);
    STAGE2(bPanel + 8192,          &Bs[0][8192]);
    STAGE2(aPanel + 8192,          &As[0][8192]);
    STAGE2(bPanel + 16384,         &Bs[1][0]);
    STAGE2(aPanel + 16384,         &As[1][0]);
    STAGE2(bPanel + 16384 + 8192,  &Bs[1][8192]);
    asm volatile("s_waitcnt vmcnt(10)" ::: "memory");   // B(0)h0, A(0)h0 landed
    __builtin_amdgcn_s_barrier();

#pragma unroll 2
    for (int tt = 0; tt < NT - 2; ++tt) {
        const int b = tt & 1;
        const ushort_t* Ac = &As[b][0];
        const ushort_t* Bc = &Bs[b][0];

        bf16x8 bF[4];

        // ph0: tm0-3 kh0; BLOAD kh0; stage A(t+1)h1 -> As[b^1]h1
        GA_PHASE(0, 0, BLOAD(0),
                 STAGE2(aPanel + (size_t)(tt + 1) * 16384 + 8192, &As[b ^ 1][8192]),
                 {})
        // ph1: tm4-7 kh0; stage B(t+2)h0 -> Bs[b]h0; wait for A(t)h1,B(t)h1
        GA_PHASE(4, 0, {},
                 STAGE2(bPanel + (size_t)(tt + 2) * 16384, &Bs[b][0]),
                 asm volatile("s_waitcnt vmcnt(10)" ::: "memory"))
        // ph2: tm0-3 kh1; BLOAD kh1; stage A(t+2)h0 -> As[b]h0
        GA_PHASE(0, 1, BLOAD(8192),
                 STAGE2(aPanel + (size_t)(tt + 2) * 16384, &As[b][0]),
                 {})
        // ph3: tm4-7 kh1; stage B(t+2)h1 -> Bs[b]h1; wait for A(t+1)h0,B(t+1)h0
        GA_PHASE(4, 1, {},
                 STAGE2(bPanel + (size_t)(tt + 2) * 16384 + 8192, &Bs[b][8192]),
                 asm volatile("s_waitcnt vmcnt(10)" ::: "memory"))
    }

    // ---- peeled iter NT-2 (b = 0): stage only A(NT-1)h1 ----
    {
        const ushort_t* Ac = &As[0][0];
        const ushort_t* Bc = &Bs[0][0];
        bf16x8 bF[4];
        GA_PHASE(0, 0, BLOAD(0),
                 STAGE2(aPanel + (size_t)(NT - 1) * 16384 + 8192, &As[1][8192]),
                 {})
        GA_PHASE(4, 0, {}, {},
                 asm volatile("s_waitcnt vmcnt(8)" ::: "memory"))
        GA_PHASE(0, 1, BLOAD(8192), {}, {})
        GA_PHASE(4, 1, {}, {},
                 asm volatile("s_waitcnt vmcnt(4)" ::: "memory"))
    }
    // ---- peeled iter NT-1 (b = 1): no stages ----
    {
        const ushort_t* Ac = &As[1][0];
        const ushort_t* Bc = &Bs[1][0];
        bf16x8 bF[4];
        GA_PHASE(0, 0, BLOAD(0), {}, {})
        GA_PHASE(4, 0, {}, {},
                 asm volatile("s_waitcnt vmcnt(0)" ::: "memory"))
        GA_PHASE(0, 1, BLOAD(8192), {}, {})
        GA_PHASE(4, 1, {}, {}, {})
    }

    // ---------- fused multivector normalization + store ----------
    // C/D 16x16 layout: col = lane&15, row = (lane>>4)*4 + reg.
    // A multivector = 32 consecutive cols = col-tile pair (2u, 2u+1).
    const int row0 = m_blk * 256 + wr * 128;
    const int col0 = n_blk * 256 + wc * 64;
#pragma unroll
    for (int tm = 0; tm < 8; ++tm) {
#pragma unroll
        for (int u = 0; u < 2; ++u) {
#pragma unroll
            for (int reg = 0; reg < 4; ++reg) {
                float v0 = acc[tm][2 * u][reg];
                float v1 = acc[tm][2 * u + 1][reg];
                float p = v0 * v0 + v1 * v1;
                p += __shfl_xor(p, 1);
                p += __shfl_xor(p, 2);
                p += __shfl_xor(p, 4);
                p += __shfl_xor(p, 8);      // stays within the 16-lane group
                const float inv = rsqrtf(p + 1e-6f);
                const int row = row0 + tm * 16 + lg * 4 + reg;
                float* orow = out + (size_t)row * 4096 + col0 + u * 32 + lm;
                orow[0]  = v0 * inv;
                orow[16] = v1 * inv;
            }
        }
    }
}

// ---------- launch ----------

extern "C" void kernel_launch(void* const* d_in, const int* in_sizes, int n_in,
                              void* d_out, int out_size, void* d_ws, size_t ws_size,
                              hipStream_t stream) {
    const float* x = (const float*)d_in[0];     // 4096 x 128 x 32 f32
    const float* w = (const float*)d_in[1];     // 128 x 128 x 32 f32
    float* out = (float*)d_out;                 // 4096 x 128 x 32 f32

    ushort_t* A_sw = (ushort_t*)d_ws;                       // 32 MiB
    ushort_t* B_sw = A_sw + (size_t)4096 * 4096;            // 32 MiB

    prepAB<<<dim3(128, 64, 2), 256, 0, stream>>>(x, w, A_sw, B_sw);
    gemm_norm<<<dim3(256), 512, 0, stream>>>(A_sw, B_sw, out);
}

// Round 3
// 229.369 us; speedup vs baseline: 1.0060x; 1.0047x over previous
//
#include <hip/hip_runtime.h>
#include <stdint.h>

typedef unsigned short ushort_t;
typedef __attribute__((ext_vector_type(8))) __bf16 bf16x8;
typedef __attribute__((ext_vector_type(4))) float  f32x4;

// ---------- helpers ----------

__device__ __forceinline__ unsigned int f2bf(float f) {
    unsigned int u = __float_as_uint(f);
    return (u + 0x7FFFu + ((u >> 16) & 1u)) >> 16;  // RNE
}

// Cayley sign for e_a * e_b in Cl(4,1), SIG = [1,1,1,1,-1]
__device__ __forceinline__ float cayley_sign(int a, int b) {
    int s = 0;
    int aa = a >> 1;
    while (aa) { s += __popc(aa & b); aa >>= 1; }
    float sign = (s & 1) ? -1.0f : 1.0f;
    if (a & b & 16) sign = -sign;   // only SIG[4] = -1
    return sign;
}

// async global->LDS, 16 bytes per lane. LDS dest is wave-uniform base + lane*16.
__device__ __forceinline__ void async16(const ushort_t* g, const ushort_t* l) {
    const __attribute__((address_space(1))) unsigned int* gp =
        (const __attribute__((address_space(1))) unsigned int*)(uintptr_t)g;
    __attribute__((address_space(3))) unsigned int* lp =
        (__attribute__((address_space(3))) unsigned int*)(unsigned int)(uintptr_t)l;
    __builtin_amdgcn_global_load_lds(gp, lp, 16, 0, 0);
}

// ---------- merged prep kernel (coalesced) — UNCHANGED from round 2 ----------
// Operand image per (panel P of 256 rows, k-tile kt of 64): 16384 bf16 laid out
// [k8(8)][row(256)][j(8)], k = k8*8+j. Each 16 KiB half = one staging half-tile.
__global__ __launch_bounds__(256) void prepAB(const float* __restrict__ x,
                                              const float* __restrict__ w,
                                              ushort_t* __restrict__ A_sw,
                                              ushort_t* __restrict__ B_sw) {
    const int k_blk = blockIdx.x;            // 0..127 (32-k chunk)
    const int p_blk = blockIdx.y >> 1;       // 0..31 (128-row panel)
    const int sub   = blockIdx.y & 1;        // 0..1  (64-row half)
    const int t = threadIdx.x;               // 0..255
    const int r  = sub * 64 + (t >> 2);      // 0..127 row/col within 128-panel
    const int kq = t & 3;                    // 0..3

    const int kt = k_blk >> 1;               // 64-k tile index (0..63)
    const int kh = k_blk & 1;                // which 32-k half of the tile

    if (blockIdx.z == 0) {
        // ---- A: x viewed as 4096 x 4096 row-major f32 -> bf16 swizzled ----
        const int R = p_blk * 128 + r;
        const float* src = x + (size_t)R * 4096 + (size_t)k_blk * 32 + kq * 8;
        float4 a = ((const float4*)src)[0];
        float4 b = ((const float4*)src)[1];
        uint4 pk;
        pk.x = f2bf(a.x) | (f2bf(a.y) << 16);
        pk.y = f2bf(a.z) | (f2bf(a.w) << 16);
        pk.z = f2bf(b.x) | (f2bf(b.y) << 16);
        pk.w = f2bf(b.z) | (f2bf(b.w) << 16);
        const int P = R >> 8, rowp = R & 255;
        *(uint4*)(A_sw + (size_t)(P * 64 + kt) * 16384 + kh * 8192 + kq * 2048 + rowp * 8) = pk;
    } else {
        // ---- B: Bt[n][f*32+i] = W[o, f, i^kc] * sgn(i, i^kc), n = o*32+kc ----
        const int n = p_blk * 128 + r;
        const int o = n >> 5;
        const int kc = n & 31;
        const float* wrow = w + (size_t)o * 4096 + (size_t)k_blk * 32;
        unsigned int pk[4];
#pragma unroll
        for (int pr = 0; pr < 4; ++pr) {
            const int i0 = kq * 8 + pr * 2, i1 = i0 + 1;
            const int j0 = i0 ^ kc, j1 = i1 ^ kc;
            float v0 = wrow[j0] * cayley_sign(i0, j0);
            float v1 = wrow[j1] * cayley_sign(i1, j1);
            pk[pr] = f2bf(v0) | (f2bf(v1) << 16);
        }
        uint4 u = {pk[0], pk[1], pk[2], pk[3]};
        const int P = n >> 8, colp = n & 255;
        *(uint4*)(B_sw + (size_t)(P * 64 + kt) * 16384 + kh * 8192 + kq * 2048 + colp * 8) = u;
    }
}

// ---------- GEMM: 256x256, BK=64, 8 waves, reg-pipelined 4-phase schedule ----------
// Phase p: { stage(p); ds_reads for phase p+1 (alternate reg set); MFMA(p);
//            [vmcnt(8) at ends of ph0/ph2]; s_barrier }.
// ds_read latency hides under MFMA; compiler emits counted lgkmcnt by dataflow.
// Every half-tile has a 4-phase issue->wait distance; vmcnt precedes the barrier
// so the landing guarantee is published to all waves before dependent reads.

#define MFMA16(a, b, c) __builtin_amdgcn_mfma_f32_16x16x32_bf16(a, b, c, 0, 0, 0)

#define RD_A4(d0, d1, d2, d3, base, KH, TMB) do {                              \
        const ushort_t* _p = (base) + aOff + (KH) * 8192 + (TMB) * 128;        \
        d0 = *(const bf16x8*)(_p + 0 * 128);                                   \
        d1 = *(const bf16x8*)(_p + 1 * 128);                                   \
        d2 = *(const bf16x8*)(_p + 2 * 128);                                   \
        d3 = *(const bf16x8*)(_p + 3 * 128);                                   \
    } while (0)

#define RD_B4(d0, d1, d2, d3, base, KH) do {                                   \
        const ushort_t* _p = (base) + bOff + (KH) * 8192;                      \
        d0 = *(const bf16x8*)(_p + 0 * 128);                                   \
        d1 = *(const bf16x8*)(_p + 1 * 128);                                   \
        d2 = *(const bf16x8*)(_p + 2 * 128);                                   \
        d3 = *(const bf16x8*)(_p + 3 * 128);                                   \
    } while (0)

#define PHASE(STAGE_STMT, RD_STMT, TMB, A0, A1, A2, A3, TAIL)                  \
    {                                                                          \
        STAGE_STMT;                                                            \
        RD_STMT;                                                               \
        __builtin_amdgcn_sched_barrier(0);                                     \
        __builtin_amdgcn_s_setprio(1);                                         \
        acc[(TMB) + 0][0] = MFMA16(A0, B0_, acc[(TMB) + 0][0]);                \
        acc[(TMB) + 0][1] = MFMA16(A0, B1_, acc[(TMB) + 0][1]);                \
        acc[(TMB) + 0][2] = MFMA16(A0, B2_, acc[(TMB) + 0][2]);                \
        acc[(TMB) + 0][3] = MFMA16(A0, B3_, acc[(TMB) + 0][3]);                \
        acc[(TMB) + 1][0] = MFMA16(A1, B0_, acc[(TMB) + 1][0]);                \
        acc[(TMB) + 1][1] = MFMA16(A1, B1_, acc[(TMB) + 1][1]);                \
        acc[(TMB) + 1][2] = MFMA16(A1, B2_, acc[(TMB) + 1][2]);                \
        acc[(TMB) + 1][3] = MFMA16(A1, B3_, acc[(TMB) + 1][3]);                \
        acc[(TMB) + 2][0] = MFMA16(A2, B0_, acc[(TMB) + 2][0]);                \
        acc[(TMB) + 2][1] = MFMA16(A2, B1_, acc[(TMB) + 2][1]);                \
        acc[(TMB) + 2][2] = MFMA16(A2, B2_, acc[(TMB) + 2][2]);                \
        acc[(TMB) + 2][3] = MFMA16(A2, B3_, acc[(TMB) + 2][3]);                \
        acc[(TMB) + 3][0] = MFMA16(A3, B0_, acc[(TMB) + 3][0]);                \
        acc[(TMB) + 3][1] = MFMA16(A3, B1_, acc[(TMB) + 3][1]);                \
        acc[(TMB) + 3][2] = MFMA16(A3, B2_, acc[(TMB) + 3][2]);                \
        acc[(TMB) + 3][3] = MFMA16(A3, B3_, acc[(TMB) + 3][3]);                \
        __builtin_amdgcn_s_setprio(0);                                         \
        TAIL;                                                                  \
        __builtin_amdgcn_s_barrier();                                          \
    }

__global__ __launch_bounds__(512, 2) void gemm_norm(const ushort_t* __restrict__ A_sw,
                                                    const ushort_t* __restrict__ B_sw,
                                                    float* __restrict__ out) {
    __shared__ ushort_t As[2][16384];   // 2 x 32 KiB
    __shared__ ushort_t Bs[2][16384];   // 2 x 32 KiB  (128 KiB total, 1 block/CU)

    // XCD-aware bijective swizzle over the 256-block grid (256 % 8 == 0)
    int id = blockIdx.x;
    id = (id & 7) * 32 + (id >> 3);
    const int m_blk = id >> 4;          // 0..15
    const int n_blk = id & 15;          // 0..15

    const int t    = threadIdx.x;
    const int wave = t >> 6;            // 0..7
    const int lane = t & 63;
    const int wr = wave >> 2;           // 0..1  (row half of 256)
    const int wc = wave & 3;            // 0..3  (64-col slice)
    const int lg = lane >> 4;           // 0..3  (k-quarter within 32-chunk)
    const int lm = lane & 15;           // 0..15 (m/n within 16-tile)

    const int aOff = (lg * 256 + wr * 128 + lm) * 8;   // elem offset into A image
    const int bOff = (lg * 256 + wc * 64  + lm) * 8;   // elem offset into B image

    const ushort_t* aPanel = A_sw + (size_t)m_blk * 64 * 16384;
    const ushort_t* bPanel = B_sw + (size_t)n_blk * 64 * 16384;

    f32x4 acc[8][4];
#pragma unroll
    for (int i = 0; i < 8; ++i)
#pragma unroll
        for (int j = 0; j < 4; ++j)
#pragma unroll
            for (int k = 0; k < 4; ++k) acc[i][j][k] = 0.0f;

    const int so = wave * 1024 + lane * 8;  // per-lane global elem offset of stage slice
    const int sl = wave * 1024;             // wave-uniform LDS elem offset

    auto STAGE2 = [&](const ushort_t* src, ushort_t* ldsb) {
        async16(src + so,       ldsb + sl);
        async16(src + so + 512, ldsb + sl + 512);
    };

    const int NT = 64;

    // prologue: 7 half-tiles in steady-state issue order (14 vm-ops):
    // B(0)h0, A(0)h0, B(0)h1, A(0)h1, B(1)h0, A(1)h0, B(1)h1
    STAGE2(bPanel + 0,             &Bs[0][0]);
    STAGE2(aPanel + 0,             &As[0][0]);
    STAGE2(bPanel + 8192,          &Bs[0][8192]);
    STAGE2(aPanel + 8192,          &As[0][8192]);
    STAGE2(bPanel + 16384,         &Bs[1][0]);
    STAGE2(aPanel + 16384,         &As[1][0]);
    STAGE2(bPanel + 16384 + 8192,  &Bs[1][8192]);
    asm volatile("s_waitcnt vmcnt(10)" ::: "memory");   // B(0)h0, A(0)h0 landed
    __builtin_amdgcn_s_barrier();

    // fragment register sets (ping-pong): aX/aY (4 each), bX/bY (4 each)
    bf16x8 aX0, aX1, aX2, aX3, aY0, aY1, aY2, aY3;
    bf16x8 bX0, bX1, bX2, bX3, bY0, bY1, bY2, bY3;

    // pre-loop reads for iter0/ph0: A(0) kh0 tm0-3, B(0) kh0
    RD_A4(aX0, aX1, aX2, aX3, &As[0][0], 0, 0);
    RD_B4(bX0, bX1, bX2, bX3, &Bs[0][0], 0);

#define B0_ bX0
#define B1_ bX1
#define B2_ bX2
#define B3_ bX3
#define C0_ bY0
#define C1_ bY1
#define C2_ bY2
#define C3_ bY3

#pragma unroll 2
    for (int tt = 0; tt < NT - 2; ++tt) {
        const int b = tt & 1;
        const ushort_t* Ac = &As[b][0];
        const ushort_t* Bc = &Bs[b][0];
        const ushort_t* An = &As[b ^ 1][0];
        const ushort_t* Bn = &Bs[b ^ 1][0];

        // ph0: MFMA(tm0-3, kh0) on aX,bX; read aY <- A kh0 tm4-7;
        //      stage A(t+1)h1 -> As[b^1]h1; end: vmcnt(8)
        PHASE(STAGE2(aPanel + (size_t)(tt + 1) * 16384 + 8192, &As[b ^ 1][8192]),
              RD_A4(aY0, aY1, aY2, aY3, Ac, 0, 4),
              0, aX0, aX1, aX2, aX3,
              asm volatile("s_waitcnt vmcnt(8)" ::: "memory"))

        // ph1: MFMA(tm4-7, kh0) on aY,bX; read aX <- A kh1 tm0-3, bY <- B kh1;
        //      stage B(t+2)h0 -> Bs[b]h0
        PHASE(STAGE2(bPanel + (size_t)(tt + 2) * 16384, &Bs[b][0]),
              RD_A4(aX0, aX1, aX2, aX3, Ac, 1, 0); RD_B4(bY0, bY1, bY2, bY3, Bc, 1),
              4, aY0, aY1, aY2, aY3,
              {})

#undef B0_
#undef B1_
#undef B2_
#undef B3_
#define B0_ bY0
#define B1_ bY1
#define B2_ bY2
#define B3_ bY3

        // ph2: MFMA(tm0-3, kh1) on aX,bY; read aY <- A kh1 tm4-7;
        //      stage A(t+2)h0 -> As[b]h0; end: vmcnt(8)
        PHASE(STAGE2(aPanel + (size_t)(tt + 2) * 16384, &As[b][0]),
              RD_A4(aY0, aY1, aY2, aY3, Ac, 1, 4),
              0, aX0, aX1, aX2, aX3,
              asm volatile("s_waitcnt vmcnt(8)" ::: "memory"))

        // ph3: MFMA(tm4-7, kh1) on aY,bY; read aX <- A(t+1) kh0 tm0-3, bX <- B(t+1) kh0;
        //      stage B(t+2)h1 -> Bs[b]h1
        PHASE(STAGE2(bPanel + (size_t)(tt + 2) * 16384 + 8192, &Bs[b][8192]),
              RD_A4(aX0, aX1, aX2, aX3, An, 0, 0); RD_B4(bX0, bX1, bX2, bX3, Bn, 0),
              4, aY0, aY1, aY2, aY3,
              {})

#undef B0_
#undef B1_
#undef B2_
#undef B3_
#define B0_ bX0
#define B1_ bX1
#define B2_ bX2
#define B3_ bX3
    }

    // ---- peeled iter NT-2 (b = 0): only stage A(NT-1)h1; waits 8 then 4 ----
    {
        const ushort_t* Ac = &As[0][0];
        const ushort_t* Bc = &Bs[0][0];
        const ushort_t* An = &As[1][0];
        const ushort_t* Bn = &Bs[1][0];

        PHASE(STAGE2(aPanel + (size_t)(NT - 1) * 16384 + 8192, &As[1][8192]),
              RD_A4(aY0, aY1, aY2, aY3, Ac, 0, 4),
              0, aX0, aX1, aX2, aX3,
              asm volatile("s_waitcnt vmcnt(8)" ::: "memory"))
        PHASE({},
              RD_A4(aX0, aX1, aX2, aX3, Ac, 1, 0); RD_B4(bY0, bY1, bY2, bY3, Bc, 1),
              4, aY0, aY1, aY2, aY3,
              {})
#undef B0_
#undef B1_
#undef B2_
#undef B3_
#define B0_ bY0
#define B1_ bY1
#define B2_ bY2
#define B3_ bY3
        PHASE({},
              RD_A4(aY0, aY1, aY2, aY3, Ac, 1, 4),
              0, aX0, aX1, aX2, aX3,
              asm volatile("s_waitcnt vmcnt(4)" ::: "memory"))
        PHASE({},
              RD_A4(aX0, aX1, aX2, aX3, An, 0, 0); RD_B4(bX0, bX1, bX2, bX3, Bn, 0),
              4, aY0, aY1, aY2, aY3,
              {})
#undef B0_
#undef B1_
#undef B2_
#undef B3_
#define B0_ bX0
#define B1_ bX1
#define B2_ bX2
#define B3_ bX3
    }
    // ---- peeled iter NT-1 (b = 1): no stages; drain to 0 at end of ph0 ----
    {
        const ushort_t* Ac = &As[1][0];
        const ushort_t* Bc = &Bs[1][0];

        PHASE({},
              RD_A4(aY0, aY1, aY2, aY3, Ac, 0, 4),
              0, aX0, aX1, aX2, aX3,
              asm volatile("s_waitcnt vmcnt(0)" ::: "memory"))
        PHASE({},
              RD_A4(aX0, aX1, aX2, aX3, Ac, 1, 0); RD_B4(bY0, bY1, bY2, bY3, Bc, 1),
              4, aY0, aY1, aY2, aY3,
              {})
#undef B0_
#undef B1_
#undef B2_
#undef B3_
#define B0_ bY0
#define B1_ bY1
#define B2_ bY2
#define B3_ bY3
        PHASE({},
              RD_A4(aY0, aY1, aY2, aY3, Ac, 1, 4),
              0, aX0, aX1, aX2, aX3,
              {})
        // final phase: MFMA only, no barrier needed after
        {
            __builtin_amdgcn_s_setprio(1);
            acc[4][0] = MFMA16(aY0, B0_, acc[4][0]);
            acc[4][1] = MFMA16(aY0, B1_, acc[4][1]);
            acc[4][2] = MFMA16(aY0, B2_, acc[4][2]);
            acc[4][3] = MFMA16(aY0, B3_, acc[4][3]);
            acc[5][0] = MFMA16(aY1, B0_, acc[5][0]);
            acc[5][1] = MFMA16(aY1, B1_, acc[5][1]);
            acc[5][2] = MFMA16(aY1, B2_, acc[5][2]);
            acc[5][3] = MFMA16(aY1, B3_, acc[5][3]);
            acc[6][0] = MFMA16(aY2, B0_, acc[6][0]);
            acc[6][1] = MFMA16(aY2, B1_, acc[6][1]);
            acc[6][2] = MFMA16(aY2, B2_, acc[6][2]);
            acc[6][3] = MFMA16(aY2, B3_, acc[6][3]);
            acc[7][0] = MFMA16(aY3, B0_, acc[7][0]);
            acc[7][1] = MFMA16(aY3, B1_, acc[7][1]);
            acc[7][2] = MFMA16(aY3, B2_, acc[7][2]);
            acc[7][3] = MFMA16(aY3, B3_, acc[7][3]);
            __builtin_amdgcn_s_setprio(0);
        }
    }

    // ---------- fused multivector normalization + store ----------
    // C/D 16x16 layout: col = lane&15, row = (lane>>4)*4 + reg.
    // A multivector = 32 consecutive cols = col-tile pair (2u, 2u+1).
    const int row0 = m_blk * 256 + wr * 128;
    const int col0 = n_blk * 256 + wc * 64;
#pragma unroll
    for (int tm = 0; tm < 8; ++tm) {
#pragma unroll
        for (int u = 0; u < 2; ++u) {
#pragma unroll
            for (int reg = 0; reg < 4; ++reg) {
                float v0 = acc[tm][2 * u][reg];
                float v1 = acc[tm][2 * u + 1][reg];
                float p = v0 * v0 + v1 * v1;
                p += __shfl_xor(p, 1);
                p += __shfl_xor(p, 2);
                p += __shfl_xor(p, 4);
                p += __shfl_xor(p, 8);      // stays within the 16-lane group
                const float inv = rsqrtf(p + 1e-6f);
                const int row = row0 + tm * 16 + lg * 4 + reg;
                float* orow = out + (size_t)row * 4096 + col0 + u * 32 + lm;
                orow[0]  = v0 * inv;
                orow[16] = v1 * inv;
            }
        }
    }
}

// ---------- launch ----------

extern "C" void kernel_launch(void* const* d_in, const int* in_sizes, int n_in,
                              void* d_out, int out_size, void* d_ws, size_t ws_size,
                              hipStream_t stream) {
    const float* x = (const float*)d_in[0];     // 4096 x 128 x 32 f32
    const float* w = (const float*)d_in[1];     // 128 x 128 x 32 f32
    float* out = (float*)d_out;                 // 4096 x 128 x 32 f32

    ushort_t* A_sw = (ushort_t*)d_ws;                       // 32 MiB
    ushort_t* B_sw = A_sw + (size_t)4096 * 4096;            // 32 MiB

    prepAB<<<dim3(128, 64, 2), 256, 0, stream>>>(x, w, A_sw, B_sw);
    gemm_norm<<<dim3(256), 512, 0, stream>>>(A_sw, B_sw, out);
}